// Round 3
// baseline (15.372 us; speedup 1.0000x reference)
//
#include <hip/hip_runtime.h>
#include <math.h>

#define Bsz 4096
#define Dd 32
#define Hh 256
#define ROWS 4
#define NBLK (Bsz / ROWS)   // 1024 blocks -> 4 blocks/CU -> 16 waves/CU
#define INTEGRAL_C 1.0f

// LDS strides (floats): float4-aligned where needed, bank-spread.
#define Z_STRIDE 36    // zs[r][d]  (broadcast reads -> conflict-free)
#define H_STRIDE 260   // hbuf[r][j], 260%32=4 -> rows land on distinct bank quads
#define G_STRIDE 257   // gbuf[r][j], scalar reads, 2-way max (free)

typedef float f32x2 __attribute__((ext_vector_type(2)));

// tanh(x) = 1 - 2/(e^{2x}+1); e^{2x} = 2^(x*2*log2(e)). Branch-free.
// overflow -> inf -> rcp -> 0 -> +1; underflow -> 0 -> rcp(1) -> -1.  Correct limits.
__device__ __forceinline__ float fast_tanh(float x) {
    const float e = exp2f(x * 2.88539008f);
    return 1.0f - 2.0f * __builtin_amdgcn_rcpf(e + 1.0f);
}

__global__ __launch_bounds__(256, 4) void ffjord_fused(
    const float* __restrict__ t,
    const float* __restrict__ z,
    const float* __restrict__ W1,
    const float* __restrict__ b1,
    const float* __restrict__ W2,
    const float* __restrict__ b2,
    float* __restrict__ f_out,
    float* __restrict__ dlogp_out)
{
    __shared__ float zs[ROWS * Z_STRIDE];      // 0.6 KB
    __shared__ float hbuf[ROWS * H_STRIDE];    // 4.1 KB
    __shared__ float gbuf[ROWS * G_STRIDE];    // 4.1 KB
    __shared__ float4 psum[256];               // 4 KB

    const int tid = threadIdx.x;
    const int row0 = blockIdx.x * ROWS;

    // ---- stage this block's 4 z rows (128 floats, coalesced) ----
    if (tid < ROWS * Dd)
        zs[(tid >> 5) * Z_STRIDE + (tid & 31)] = z[row0 * Dd + tid];

    // ---- W1 column j=tid (z-part) into f32x2 pairs for pk-fma ----
    f32x2 w1p[Dd / 2];
#pragma unroll
    for (int k = 0; k < Dd / 2; ++k) {
        w1p[k].x = W1[(1 + 2 * k) * Hh + tid];
        w1p[k].y = W1[(2 + 2 * k) * Hh + tid];
    }

    const float tval = t[0];
    const float scale = 1.0f / sqrtf(1.0f - __expf(-(INTEGRAL_C * tval * tval)));
    const float coef = -INTEGRAL_C * tval;          // f = coef*(z - scale*out)
    const float ubase = b1[tid] + tval * W1[tid];   // t*W1[0][j] + b1[j]

    // ---- c_j = sum_d W1[1+d][j] * W2[j][d]  (packed fp32) ----
    f32x2 c2a = {0.f, 0.f}, c2b = {0.f, 0.f};
#pragma unroll
    for (int q = 0; q < 8; ++q) {
        const float4 w2v = *(const float4*)&W2[tid * Dd + q * 4];
        f32x2 lo; lo.x = w2v.x; lo.y = w2v.y;
        f32x2 hi; hi.x = w2v.z; hi.y = w2v.w;
        c2a += w1p[2 * q] * lo;
        c2b += w1p[2 * q + 1] * hi;
    }
    const f32x2 c2 = c2a + c2b;
    const float c = c2.x + c2.y;

    __syncthreads();

    // ---- phase 1: h + trace weight for 4 rows (packed fp32, 2 acc/row) ----
#pragma unroll
    for (int r = 0; r < ROWS; ++r) {
        f32x2 ua = {0.f, 0.f}, ub = {0.f, 0.f};
#pragma unroll
        for (int q = 0; q < 8; ++q) {
            const float4 zq = *(const float4*)&zs[r * Z_STRIDE + q * 4];  // broadcast
            f32x2 zlo; zlo.x = zq.x; zlo.y = zq.y;
            f32x2 zhi; zhi.x = zq.z; zhi.y = zq.w;
            ua += w1p[2 * q] * zlo;
            ub += w1p[2 * q + 1] * zhi;
        }
        const f32x2 us = ua + ub;
        const float h = fast_tanh(ubase + us.x + us.y);
        hbuf[r * H_STRIDE + tid] = h;
        gbuf[r * G_STRIDE + tid] = (1.0f - h * h) * c;
    }
    __syncthreads();

    // ---- phase 2: out = h @ W2. tid = jq*32 + r*8 + i4 (packed fp32) ----
    {
        const int i4 = tid & 7;          // column group (4 cols)
        const int r  = (tid >> 3) & 3;   // row
        const int jq = tid >> 5;         // j-range [32*jq, 32*jq+32)
        f32x2 a01 = {0.f, 0.f}, a23 = {0.f, 0.f};
        const int j0 = jq * 32;
#pragma unroll
        for (int j = j0; j < j0 + 32; j += 4) {
            const float4 h4 = *(const float4*)&hbuf[r * H_STRIDE + j];
#pragma unroll
            for (int k = 0; k < 4; ++k) {
                const float4 wv = *(const float4*)&W2[(j + k) * Dd + i4 * 4];
                const float hk = (k == 0) ? h4.x : (k == 1) ? h4.y : (k == 2) ? h4.z : h4.w;
                f32x2 hs; hs.x = hk; hs.y = hk;
                f32x2 wlo; wlo.x = wv.x; wlo.y = wv.y;
                f32x2 whi; whi.x = wv.z; whi.y = wv.w;
                a01 += hs * wlo;
                a23 += hs * whi;
            }
        }
        float4 acc;
        acc.x = a01.x; acc.y = a01.y; acc.z = a23.x; acc.w = a23.y;
        psum[tid] = acc;   // tid == jq*32 + r*8 + i4
    }

    // ---- trace reduce: wave rr owns row rr (gbuf written pre-barrier) ----
    {
        const int rr = tid >> 6;        // wave id == row
        const int k  = tid & 63;
        float v = gbuf[rr * G_STRIDE + k]       + gbuf[rr * G_STRIDE + k + 64] +
                  gbuf[rr * G_STRIDE + k + 128] + gbuf[rr * G_STRIDE + k + 192];
#pragma unroll
        for (int off = 32; off > 0; off >>= 1)
            v += __shfl_xor(v, off, 64);
        if (k == 0)
            dlogp_out[row0 + rr] = INTEGRAL_C * tval * ((float)Dd - scale * v);
    }
    __syncthreads();

    // ---- combine 8 j-quarters + epilogue: f = coef*(z - scale*(out+b2)) ----
    if (tid < 32) {
        const int i4 = tid & 7;
        const int r  = tid >> 3;
        float4 s;
        s.x = s.y = s.z = s.w = 0.0f;
#pragma unroll
        for (int m = 0; m < 8; ++m) {
            const float4 p = psum[m * 32 + tid];
            s.x += p.x; s.y += p.y; s.z += p.z; s.w += p.w;
        }
        const float4 b2v = *(const float4*)&b2[i4 * 4];
        const float4 zv  = *(const float4*)&zs[r * Z_STRIDE + i4 * 4];
        float4 o;
        o.x = coef * (zv.x - scale * (s.x + b2v.x));
        o.y = coef * (zv.y - scale * (s.y + b2v.y));
        o.z = coef * (zv.z - scale * (s.z + b2v.z));
        o.w = coef * (zv.w - scale * (s.w + b2v.w));
        *(float4*)&f_out[(row0 + r) * Dd + i4 * 4] = o;
    }
}

extern "C" void kernel_launch(void* const* d_in, const int* in_sizes, int n_in,
                              void* d_out, int out_size, void* d_ws, size_t ws_size,
                              hipStream_t stream) {
    const float* t  = (const float*)d_in[0];
    const float* z  = (const float*)d_in[1];
    const float* W1 = (const float*)d_in[2];
    const float* b1 = (const float*)d_in[3];
    const float* W2 = (const float*)d_in[4];
    const float* b2 = (const float*)d_in[5];
    float* f_out = (float*)d_out;
    float* dlogp_out = f_out + Bsz * Dd;

    ffjord_fused<<<NBLK, 256, 0, stream>>>(t, z, W1, b1, W2, b2, f_out, dlogp_out);
}